// Round 1
// baseline (456.264 us; speedup 1.0000x reference)
//
#include <hip/hip_runtime.h>
#include <hip/hip_bf16.h>

// FeatureAttention: B=4,T=2048,D=2048,H=16,HO=128
// out = ( softmax(qh^T kh / sqrt(HO)) applied over features, @ (v+alibi)^T )^T @ Wp + bp
// alibi folded into ctx epilogue since softmax rows sum to 1.

#define Tt 2048
#define Dd 2048
#define Mm 8192   // B*T

typedef __attribute__((ext_vector_type(4))) float f32x4;
typedef __attribute__((ext_vector_type(8))) short s16x8;
static_assert(sizeof(s16x8) == 16, "frag size");

typedef const __attribute__((address_space(1))) void* gptr_t;
typedef __attribute__((address_space(3))) void* lptr_t;

__device__ __forceinline__ float bf2f(ushort u) {
    union { unsigned int i; float f; } c; c.i = ((unsigned int)u) << 16; return c.f;
}
__device__ __forceinline__ ushort f2bf(float f) {
    union { float f; unsigned int i; } c; c.f = f;
    return (ushort)((c.i + 0x7FFFu + ((c.i >> 16) & 1u)) >> 16);
}
__device__ __forceinline__ void gload16(const void* g, void* l) {
    __builtin_amdgcn_global_load_lds((gptr_t)g, (lptr_t)l, 16, 0, 0);
}

// ---------------- conversions ----------------

__global__ __launch_bounds__(256) void convx_kernel(const float* __restrict__ x,
                                                    ushort* __restrict__ xb) {
    const int idx = blockIdx.x * 256 + threadIdx.x;
    const int stride = gridDim.x * 256;
    for (int i = idx; i < Mm * Dd / 4; i += stride) {
        const float4 v = *(const float4*)(x + (size_t)i * 4);
        ushort4 o; o.x = f2bf(v.x); o.y = f2bf(v.y); o.z = f2bf(v.z); o.w = f2bf(v.w);
        *(ushort4*)(xb + (size_t)i * 4) = o;
    }
}

// W [K=d_in][N=d_out] fp32 -> Wt [N][K] bf16 (so MFMA B-fragments read contiguous k)
__global__ __launch_bounds__(256) void transw_kernel(const float* __restrict__ W0,
        const float* __restrict__ W1, const float* __restrict__ W2,
        const float* __restrict__ W3, ushort* __restrict__ Wt) {
    __shared__ float tile[64][65];
    const int z = blockIdx.z;
    const float* W = (z == 0) ? W0 : (z == 1) ? W1 : (z == 2) ? W2 : W3;
    ushort* dst = Wt + (size_t)z * ((size_t)Dd * Dd);
    const int n0 = blockIdx.x * 64, k0 = blockIdx.y * 64;
    const int r4 = threadIdx.x >> 6, c = threadIdx.x & 63;
#pragma unroll
    for (int i = 0; i < 16; i++) {
        const int row = i * 4 + r4;
        tile[row][c] = W[(size_t)(k0 + row) * Dd + n0 + c];
    }
    __syncthreads();
#pragma unroll
    for (int i = 0; i < 16; i++) {
        const int row = i * 4 + r4;
        dst[(size_t)(n0 + row) * Dd + k0 + c] = f2bf(tile[c][row]);
    }
}

// ---------------- GEMM: C[M,N] = A[M,K] * Bt[N,K]^T  (bf16 in, fp32 acc) ----------------
// MODE 0: C bf16.   MODE 1: batched per (b,h) ctx GEMM, + alibi, C bf16.
// MODE 2: C fp32 + bias.
// 128x128 tile, BK=32, 4 waves, global_load_lds(16B), 16x16x32 bf16 MFMA (asm).

template <int MODE>
__global__ __launch_bounds__(256, 2) void gemm_kernel(
        const ushort* __restrict__ A, const ushort* __restrict__ Bt,
        void* __restrict__ Cv, const float* __restrict__ bias,
        int Kdim, int lda, int ldb, int ldc) {
    __shared__ ushort lsA[128 * 32];
    __shared__ ushort lsB[128 * 32];

    const int tid = threadIdx.x;
    const int w = tid >> 6, lane = tid & 63;
    const int m0 = blockIdx.y * 128;
    const int n0 = blockIdx.x * 128;

    const ushort* Ab = A;
    const ushort* Bb = Bt;
    size_t coff = 0;
    if (MODE == 1) {
        const int z = blockIdx.z, b = z >> 4, h = z & 15;
        const size_t ao = (size_t)b * ((size_t)Tt * Dd) + (size_t)h * 128;
        Ab += ao; Bb += (size_t)z * (128 * 128); coff = ao;
    }

    // staging: 8 chunks of 1KB per tile; wave w stages chunks {w, w+4}
    const int sr = lane >> 2;            // row within chunk (16 rows/chunk)
    const int sc = (lane & 3) * 8;       // k-element offset (16B per lane)
    const int c0 = w, c1 = w + 4;
    const int rA0 = c0 * 16 + sr, rA1 = c1 * 16 + sr;

    const int fr = lane & 15, fq = lane >> 4;
    const int wr = (w >> 1) * 64, wc = (w & 1) * 64;

    f32x4 acc[4][4];
#pragma unroll
    for (int i = 0; i < 4; i++)
#pragma unroll
        for (int j = 0; j < 4; j++) acc[i][j] = {0.f, 0.f, 0.f, 0.f};

    for (int kt = 0; kt < Kdim; kt += 32) {
        gload16(Ab + (size_t)(m0 + rA0) * lda + kt + sc, lsA + c0 * 512);
        gload16(Ab + (size_t)(m0 + rA1) * lda + kt + sc, lsA + c1 * 512);
        gload16(Bb + (size_t)(n0 + rA0) * ldb + kt + sc, lsB + c0 * 512);
        gload16(Bb + (size_t)(n0 + rA1) * ldb + kt + sc, lsB + c1 * 512);
        __syncthreads();

        s16x8 afrag[4], bfrag[4];
#pragma unroll
        for (int i = 0; i < 4; i++)
            afrag[i] = *(const s16x8*)(lsA + (wr + i * 16 + fr) * 32 + fq * 8);
#pragma unroll
        for (int j = 0; j < 4; j++)
            bfrag[j] = *(const s16x8*)(lsB + (wc + j * 16 + fr) * 32 + fq * 8);
#pragma unroll
        for (int i = 0; i < 4; i++)
#pragma unroll
            for (int j = 0; j < 4; j++)
                asm("v_mfma_f32_16x16x32_bf16 %0, %1, %2, %0"
                    : "+v"(acc[i][j]) : "v"(afrag[i]), "v"(bfrag[j]));
        __syncthreads();
    }

    asm volatile("s_nop 7\ns_nop 7\ns_nop 7");  // MFMA->VALU hazard guard

    if (MODE == 2) {
        float* C = (float*)Cv;
#pragma unroll
        for (int i = 0; i < 4; i++)
#pragma unroll
            for (int j = 0; j < 4; j++)
#pragma unroll
                for (int r = 0; r < 4; r++) {
                    const int row = m0 + wr + i * 16 + fq * 4 + r;
                    const int col = n0 + wc + j * 16 + fr;
                    C[(size_t)row * ldc + col] = acc[i][j][r] + bias[col];
                }
    } else {
        ushort* C = (ushort*)Cv + coff;
#pragma unroll
        for (int i = 0; i < 4; i++)
#pragma unroll
            for (int j = 0; j < 4; j++)
#pragma unroll
                for (int r = 0; r < 4; r++) {
                    const int row = m0 + wr + i * 16 + fq * 4 + r;
                    const int col = n0 + wc + j * 16 + fr;
                    float val = acc[i][j][r];
                    if (MODE == 1) val += 1.0f / (float)(Tt - row);  // feature alibi
                    C[(size_t)row * ldc + col] = f2bf(val);
                }
    }
}

// ---------------- scores: part[s][bh][f][g] = sum_{t in split s} q[t,f] k[t,g] ----------------

__global__ __launch_bounds__(256) void scores_kernel(const ushort* __restrict__ q,
        const ushort* __restrict__ k, float* __restrict__ part) {
    __shared__ float lsQ[32][128];
    __shared__ float lsK[32][128];
    const int tid = threadIdx.x;
    const int s = blockIdx.x, bh = blockIdx.y;
    const int b = bh >> 4, h = bh & 15;
    const size_t base = (size_t)b * ((size_t)Tt * Dd) + (size_t)h * 128;
    const ushort* qb = q + base;
    const ushort* kb = k + base;
    const int ty = tid >> 4, tx = tid & 15;
    const int f0 = ty * 8, g0 = tx * 8;

    float acc[8][8];
#pragma unroll
    for (int i = 0; i < 8; i++)
#pragma unroll
        for (int j = 0; j < 8; j++) acc[i][j] = 0.f;

    for (int ch = 0; ch < 8; ch++) {
        const int t0 = s * 256 + ch * 32;
#pragma unroll
        for (int ii = 0; ii < 4; ii++) {
            const int e = ii * 1024 + tid * 4;
            const int r = e >> 7, cc = e & 127;
            const size_t ga = (size_t)(t0 + r) * Dd + cc;
            const ushort4 v4 = *(const ushort4*)(qb + ga);
            f32x4 qf = {bf2f(v4.x), bf2f(v4.y), bf2f(v4.z), bf2f(v4.w)};
            *(f32x4*)&lsQ[r][cc] = qf;
            const ushort4 w4 = *(const ushort4*)(kb + ga);
            f32x4 kf = {bf2f(w4.x), bf2f(w4.y), bf2f(w4.z), bf2f(w4.w)};
            *(f32x4*)&lsK[r][cc] = kf;
        }
        __syncthreads();
#pragma unroll 4
        for (int tl = 0; tl < 32; tl++) {
            float qv[8], kv[8];
            *(f32x4*)&qv[0] = *(const f32x4*)&lsQ[tl][f0];
            *(f32x4*)&qv[4] = *(const f32x4*)&lsQ[tl][f0 + 4];
            *(f32x4*)&kv[0] = *(const f32x4*)&lsK[tl][g0];
            *(f32x4*)&kv[4] = *(const f32x4*)&lsK[tl][g0 + 4];
#pragma unroll
            for (int i = 0; i < 8; i++)
#pragma unroll
                for (int j = 0; j < 8; j++)
                    acc[i][j] = fmaf(qv[i], kv[j], acc[i][j]);
        }
        __syncthreads();
    }
    float* pb = part + ((size_t)s * 64 + bh) * 16384;
#pragma unroll
    for (int i = 0; i < 8; i++) {
        f32x4 o0 = {acc[i][0], acc[i][1], acc[i][2], acc[i][3]};
        f32x4 o1 = {acc[i][4], acc[i][5], acc[i][6], acc[i][7]};
        *(f32x4*)&pb[(f0 + i) * 128 + g0] = o0;
        *(f32x4*)&pb[(f0 + i) * 128 + g0 + 4] = o1;
    }
}

// ---------------- softmax over g: wts[bh][f][g] bf16 ----------------

__global__ __launch_bounds__(256) void softmax_kernel(const float* __restrict__ part,
                                                      ushort* __restrict__ wts) {
    const int tid = threadIdx.x;
    const int wv = tid >> 6, lane = tid & 63;
    const int row = blockIdx.x * 4 + wv;  // row = bh*128 + f, in [0, 8192)
    const float* p = part + (size_t)row * 128 + lane * 2;
    float v0 = 0.f, v1 = 0.f;
#pragma unroll
    for (int s = 0; s < 8; s++) {
        const float2 t = *(const float2*)(p + (size_t)s * 1048576);
        v0 += t.x; v1 += t.y;
    }
    const float sc = 0.088388347648318447f;  // 1/sqrt(128)
    v0 *= sc; v1 *= sc;
    float m = fmaxf(v0, v1);
#pragma unroll
    for (int off = 32; off > 0; off >>= 1) m = fmaxf(m, __shfl_xor(m, off));
    const float e0 = __expf(v0 - m), e1 = __expf(v1 - m);
    float smv = e0 + e1;
#pragma unroll
    for (int off = 32; off > 0; off >>= 1) smv += __shfl_xor(smv, off);
    const float inv = 1.0f / smv;
    ushort2 o; o.x = f2bf(e0 * inv); o.y = f2bf(e1 * inv);
    *(ushort2*)(wts + (size_t)row * 128 + lane * 2) = o;
}

// ---------------- launch ----------------

extern "C" void kernel_launch(void* const* d_in, const int* in_sizes, int n_in,
                              void* d_out, int out_size, void* d_ws, size_t ws_size,
                              hipStream_t stream) {
    const float* x  = (const float*)d_in[0];
    const float* Wq = (const float*)d_in[1];
    const float* Wk = (const float*)d_in[2];
    const float* Wv = (const float*)d_in[3];
    const float* Wp = (const float*)d_in[4];
    const float* bp = (const float*)d_in[5];
    float* out = (float*)d_out;
    char* ws = (char*)d_ws;

    // ws layout (MB offsets): xb/ctx 0..32 | Wt 33..65 | q 65..97 | k 97..129
    //                         | v 129..161 | part 161..193 | wts 193..195
    ushort* xb   = (ushort*)(ws);
    ushort* Wt   = (ushort*)(ws + (33ull << 20));
    ushort* q    = (ushort*)(ws + (65ull << 20));
    ushort* k    = (ushort*)(ws + (97ull << 20));
    ushort* v    = (ushort*)(ws + (129ull << 20));
    float*  part = (float*) (ws + (161ull << 20));
    ushort* wts  = (ushort*)(ws + (193ull << 20));
    ushort* ctx  = xb;  // xb dead after v-GEMM; reuse for ctx

    const size_t WSZ = (size_t)Dd * Dd;  // elements per transposed weight

    convx_kernel<<<2048, 256, 0, stream>>>(x, xb);
    transw_kernel<<<dim3(32, 32, 4), 256, 0, stream>>>(Wq, Wk, Wv, Wp, Wt);

    // q, k, v projections: [8192,2048] x [2048,2048]
    gemm_kernel<0><<<dim3(16, 64, 1), 256, 0, stream>>>(xb, Wt,           q, nullptr, 2048, 2048, 2048, 2048);
    gemm_kernel<0><<<dim3(16, 64, 1), 256, 0, stream>>>(xb, Wt + WSZ,     k, nullptr, 2048, 2048, 2048, 2048);
    gemm_kernel<0><<<dim3(16, 64, 1), 256, 0, stream>>>(xb, Wt + 2 * WSZ, v, nullptr, 2048, 2048, 2048, 2048);

    scores_kernel<<<dim3(8, 64), 256, 0, stream>>>(q, k, part);
    softmax_kernel<<<2048, 256, 0, stream>>>(part, wts);

    // ctx[t,f] = sum_g v[t,g] * wts[f,g] + alibi[t], per (b,h)
    gemm_kernel<1><<<dim3(1, 16, 64), 256, 0, stream>>>(v, wts, ctx, nullptr, 128, 2048, 128, 2048);

    // out = ctx @ Wp + bp  (fp32 out)
    gemm_kernel<2><<<dim3(16, 64, 1), 256, 0, stream>>>(ctx, Wt + 3 * WSZ, out, bp, 2048, 2048, 2048, 2048);
}

// Round 2
// 382.580 us; speedup vs baseline: 1.1926x; 1.1926x over previous
//
#include <hip/hip_runtime.h>
#include <hip/hip_bf16.h>

// FeatureAttention: B=4,T=2048,D=2048,H=16,HO=128
// alibi folded into ctx epilogue since softmax rows sum to 1.

#define Tt 2048
#define Dd 2048
#define Mm 8192   // B*T

typedef __attribute__((ext_vector_type(4))) float f32x4;
typedef __attribute__((ext_vector_type(8))) short s16x8;
static_assert(sizeof(s16x8) == 16, "frag size");

typedef const __attribute__((address_space(1))) void* gptr_t;
typedef __attribute__((address_space(3))) void* lptr_t;

__device__ __forceinline__ float bf2f(ushort u) {
    union { unsigned int i; float f; } c; c.i = ((unsigned int)u) << 16; return c.f;
}
__device__ __forceinline__ ushort f2bf(float f) {
    union { float f; unsigned int i; } c; c.f = f;
    return (ushort)((c.i + 0x7FFFu + ((c.i >> 16) & 1u)) >> 16);
}
__device__ __forceinline__ void gload16(const void* g, void* l) {
    __builtin_amdgcn_global_load_lds((gptr_t)g, (lptr_t)l, 16, 0, 0);
}

#define MFMA_BF16(d, a, b) \
    asm("v_mfma_f32_16x16x32_bf16 %0, %1, %2, %0" : "+v"(d) : "v"(a), "v"(b))

// ---------------- conversions ----------------

__global__ __launch_bounds__(256) void convx_kernel(const float* __restrict__ x,
                                                    ushort* __restrict__ xb) {
    const int idx = blockIdx.x * 256 + threadIdx.x;
    const int stride = gridDim.x * 256;
    for (int i = idx; i < Mm * Dd / 4; i += stride) {
        const float4 v = *(const float4*)(x + (size_t)i * 4);
        ushort4 o; o.x = f2bf(v.x); o.y = f2bf(v.y); o.z = f2bf(v.z); o.w = f2bf(v.w);
        *(ushort4*)(xb + (size_t)i * 4) = o;
    }
}

// W [K=d_in][N=d_out] fp32 -> Wt [N][K] bf16
__global__ __launch_bounds__(256) void transw_kernel(const float* __restrict__ W0,
        const float* __restrict__ W1, const float* __restrict__ W2,
        const float* __restrict__ W3, ushort* __restrict__ Wt) {
    __shared__ float tile[64][65];
    const int z = blockIdx.z;
    const float* W = (z == 0) ? W0 : (z == 1) ? W1 : (z == 2) ? W2 : W3;
    ushort* dst = Wt + (size_t)z * ((size_t)Dd * Dd);
    const int n0 = blockIdx.x * 64, k0 = blockIdx.y * 64;
    const int r4 = threadIdx.x >> 6, c = threadIdx.x & 63;
#pragma unroll
    for (int i = 0; i < 16; i++) {
        const int row = i * 4 + r4;
        tile[row][c] = W[(size_t)(k0 + row) * Dd + n0 + c];
    }
    __syncthreads();
#pragma unroll
    for (int i = 0; i < 16; i++) {
        const int row = i * 4 + r4;
        dst[(size_t)(n0 + row) * Dd + k0 + c] = f2bf(tile[c][row]);
    }
}

// ---------------- 256x256 8-phase GEMM: C[M,N] = A[M,K] * Bt[N,K]^T ----------------
// bf16 in, fp32 acc. MODE 0: C bf16. MODE 2: C fp32 + bias.
// 512 threads = 8 waves (2M x 4N), BK=64, 128 KiB LDS double-buffer,
// T2 XOR-swizzle (phys = logical ^ ((row&7)<<4)), counted vmcnt(4), setprio.
// Requires M%256==0, N==2048 (8 n-tiles), K%64==0, K>=128.

// stage one half-tile (128 rows x 64 k, 16 KB) of A or B into an LDS region.
// ldsRegion: byte base of the 32 KB A or B region; gRegion: global tile base
// (already includes the K-tile column offset); ld: row stride in elements.
__device__ __forceinline__ void stage_half(char* ldsRegion, const ushort* gRegion,
                                           int ld, int half, int tid) {
#pragma unroll
    for (int j = 0; j < 2; j++) {
        const int Pb = half * 16384 + j * 8192 + (tid >> 6) * 1024;  // wave-uniform
        const int P = Pb + (tid & 63) * 16;                          // this lane's slot
        const int row = P >> 7;
        const int colb = (P ^ ((row & 7) << 4)) & 127;               // logical col bytes
        gload16(gRegion + (size_t)row * ld + (colb >> 1), ldsRegion + Pb);
    }
}

template <int MODE>
__global__ __launch_bounds__(512, 2) void gemm256_kernel(
        const ushort* __restrict__ A, const ushort* __restrict__ Bt,
        void* __restrict__ Cv, const float* __restrict__ bias,
        int Kdim, int lda, int ldb, int ldc) {
    extern __shared__ char lds[];   // 2 buffers x (A 32768 + B 32768) = 131072 B

    const int tid = threadIdx.x;
    const int w = tid >> 6, lane = tid & 63;
    const int wr = w >> 2, wc = w & 3;        // 2 x 4 waves
    const int fr = lane & 15, fq = lane >> 4;

    // XCD-aware bijective swizzle (nwg = 256 = 8 XCDs x 32)
    const int bid = blockIdx.x;
    const int wg = (bid & 7) * 32 + (bid >> 3);
    const int m0 = (wg >> 3) * 256;
    const int n0 = (wg & 7) * 256;

    const ushort* Ag = A + (size_t)m0 * lda;
    const ushort* Bg = Bt + (size_t)n0 * ldb;
    const int NT = Kdim >> 6;

    // per-thread invariant LDS read offsets (T2 swizzle: row&7 == fr&7)
    const int aoff = wr * 16384 + fr * 128;
    const int boff = wc * 8192 + fr * 128;
    const int xo = (fr & 7) << 4;
    const int cp0 = (fq * 16) ^ xo;           // k-sub 0
    const int cp1 = (64 + fq * 16) ^ xo;      // k-sub 1

    f32x4 acc[8][4];
#pragma unroll
    for (int i = 0; i < 8; i++)
#pragma unroll
        for (int j = 0; j < 4; j++) acc[i][j] = {0.f, 0.f, 0.f, 0.f};

    // ---- prologue: K-tile 0 (4 half-tiles) + B-lo(1) + A-lo(1) ----
    {
        char* b0 = lds;
        char* b1 = lds + 65536;
        stage_half(b0,          Ag, lda, 0, tid);       // A-lo(0)
        stage_half(b0,          Ag, lda, 1, tid);       // A-hi(0)
        stage_half(b0 + 32768,  Bg, ldb, 0, tid);       // B-lo(0)
        stage_half(b0 + 32768,  Bg, ldb, 1, tid);       // B-hi(0)
        stage_half(b1 + 32768,  Bg + 64, ldb, 0, tid);  // B-lo(1)
        stage_half(b1,          Ag + 64, lda, 0, tid);  // A-lo(1)
        asm volatile("s_waitcnt vmcnt(4)" ::: "memory");
        __builtin_amdgcn_s_barrier();
    }

    s16x8 af[8];
    s16x8 bf[4][2];

    for (int t = 0; t < NT; ++t) {
        char* bufc = lds + (t & 1) * 65536;
        char* bufn = lds + ((t & 1) ^ 1) * 65536;

        // ================ P0: read A.k0 (8) + B.k0 (4); stage A-hi(t+1) ================
        if (t + 1 < NT) stage_half(bufn, Ag + (size_t)(t + 1) * 64, lda, 1, tid);
        {
            const char* pA = bufc + aoff + cp0;
#pragma unroll
            for (int mi = 0; mi < 8; mi++) af[mi] = *(const s16x8*)(pA + mi * 2048);
            const char* pB = bufc + 32768 + boff + cp0;
#pragma unroll
            for (int ni = 0; ni < 4; ni++) bf[ni][0] = *(const s16x8*)(pB + ni * 2048);
        }
        __builtin_amdgcn_sched_barrier(0);
        __builtin_amdgcn_s_barrier();
        asm volatile("s_waitcnt lgkmcnt(0)" ::: "memory");
        __builtin_amdgcn_sched_barrier(0);
        __builtin_amdgcn_s_setprio(1);
#pragma unroll
        for (int mi = 0; mi < 4; mi++)
#pragma unroll
            for (int ni = 0; ni < 4; ni++) MFMA_BF16(acc[mi][ni], af[mi], bf[ni][0]);
        __builtin_amdgcn_s_setprio(0);
        __builtin_amdgcn_sched_barrier(0);
        __builtin_amdgcn_s_barrier();

        // ================ P1: read B.k1 (4); stage B-hi(t+1) ================
        if (t + 1 < NT) stage_half(bufn + 32768, Bg + (size_t)(t + 1) * 64, ldb, 1, tid);
        {
            const char* pB = bufc + 32768 + boff + cp1;
#pragma unroll
            for (int ni = 0; ni < 4; ni++) bf[ni][1] = *(const s16x8*)(pB + ni * 2048);
        }
        __builtin_amdgcn_sched_barrier(0);
        __builtin_amdgcn_s_barrier();
        asm volatile("s_waitcnt lgkmcnt(0)" ::: "memory");
        __builtin_amdgcn_sched_barrier(0);
        __builtin_amdgcn_s_setprio(1);
#pragma unroll
        for (int mi = 4; mi < 8; mi++)
#pragma unroll
            for (int ni = 0; ni < 4; ni++) MFMA_BF16(acc[mi][ni], af[mi], bf[ni][0]);
        __builtin_amdgcn_s_setprio(0);
        __builtin_amdgcn_sched_barrier(0);
        __builtin_amdgcn_s_barrier();

        // ================ P2: read A.k1 (8); stage B-lo(t+2) ================
        if (t + 2 < NT) stage_half(bufc + 32768, Bg + (size_t)(t + 2) * 64, ldb, 0, tid);
        {
            const char* pA = bufc + aoff + cp1;
#pragma unroll
            for (int mi = 0; mi < 8; mi++) af[mi] = *(const s16x8*)(pA + mi * 2048);
        }
        __builtin_amdgcn_sched_barrier(0);
        __builtin_amdgcn_s_barrier();
        asm volatile("s_waitcnt lgkmcnt(0)" ::: "memory");
        __builtin_amdgcn_sched_barrier(0);
        __builtin_amdgcn_s_setprio(1);
#pragma unroll
        for (int mi = 0; mi < 4; mi++)
#pragma unroll
            for (int ni = 0; ni < 4; ni++) MFMA_BF16(acc[mi][ni], af[mi], bf[ni][1]);
        __builtin_amdgcn_s_setprio(0);
        __builtin_amdgcn_sched_barrier(0);
        __builtin_amdgcn_s_barrier();

        // ================ P3: stage A-lo(t+2); MFMA rest; counted vmcnt ================
        if (t + 2 < NT) stage_half(bufc, Ag + (size_t)(t + 2) * 64, lda, 0, tid);
        __builtin_amdgcn_sched_barrier(0);
        __builtin_amdgcn_s_setprio(1);
#pragma unroll
        for (int mi = 4; mi < 8; mi++)
#pragma unroll
            for (int ni = 0; ni < 4; ni++) MFMA_BF16(acc[mi][ni], af[mi], bf[ni][1]);
        __builtin_amdgcn_s_setprio(0);
        __builtin_amdgcn_sched_barrier(0);
        if (t < NT - 2) {
            asm volatile("s_waitcnt vmcnt(4)" ::: "memory");   // K-tile t+1 landed
        } else {
            asm volatile("s_waitcnt vmcnt(0)" ::: "memory");
        }
        __builtin_amdgcn_s_barrier();
    }

    asm volatile("s_nop 7\ns_nop 7\ns_nop 7");  // MFMA->VALU hazard guard

    if (MODE == 2) {
        float* C = (float*)Cv;
#pragma unroll
        for (int mi = 0; mi < 8; mi++)
#pragma unroll
            for (int ni = 0; ni < 4; ni++)
#pragma unroll
                for (int r = 0; r < 4; r++) {
                    const int row = m0 + wr * 128 + mi * 16 + fq * 4 + r;
                    const int col = n0 + wc * 64 + ni * 16 + fr;
                    C[(size_t)row * ldc + col] = acc[mi][ni][r] + bias[col];
                }
    } else {
        ushort* C = (ushort*)Cv;
#pragma unroll
        for (int mi = 0; mi < 8; mi++)
#pragma unroll
            for (int ni = 0; ni < 4; ni++)
#pragma unroll
                for (int r = 0; r < 4; r++) {
                    const int row = m0 + wr * 128 + mi * 16 + fq * 4 + r;
                    const int col = n0 + wc * 64 + ni * 16 + fr;
                    C[(size_t)row * ldc + col] = f2bf(acc[mi][ni][r]);
                }
    }
}

// ---------------- 128x128 GEMM (kept for the small batched ctx GEMM) ----------------
// MODE 1: batched per (b,h) ctx GEMM, + alibi, C bf16.

template <int MODE>
__global__ __launch_bounds__(256, 2) void gemm_kernel(
        const ushort* __restrict__ A, const ushort* __restrict__ Bt,
        void* __restrict__ Cv, const float* __restrict__ bias,
        int Kdim, int lda, int ldb, int ldc) {
    __shared__ ushort lsA[128 * 32];
    __shared__ ushort lsB[128 * 32];

    const int tid = threadIdx.x;
    const int w = tid >> 6, lane = tid & 63;
    const int m0 = blockIdx.y * 128;
    const int n0 = blockIdx.x * 128;

    const ushort* Ab = A;
    const ushort* Bb = Bt;
    size_t coff = 0;
    if (MODE == 1) {
        const int z = blockIdx.z, b = z >> 4, h = z & 15;
        const size_t ao = (size_t)b * ((size_t)Tt * Dd) + (size_t)h * 128;
        Ab += ao; Bb += (size_t)z * (128 * 128); coff = ao;
    }

    const int sr = lane >> 2;
    const int sc = (lane & 3) * 8;
    const int c0 = w, c1 = w + 4;
    const int rA0 = c0 * 16 + sr, rA1 = c1 * 16 + sr;

    const int fr = lane & 15, fq = lane >> 4;
    const int wr = (w >> 1) * 64, wc = (w & 1) * 64;

    f32x4 acc[4][4];
#pragma unroll
    for (int i = 0; i < 4; i++)
#pragma unroll
        for (int j = 0; j < 4; j++) acc[i][j] = {0.f, 0.f, 0.f, 0.f};

    for (int kt = 0; kt < Kdim; kt += 32) {
        gload16(Ab + (size_t)(m0 + rA0) * lda + kt + sc, lsA + c0 * 512);
        gload16(Ab + (size_t)(m0 + rA1) * lda + kt + sc, lsA + c1 * 512);
        gload16(Bb + (size_t)(n0 + rA0) * ldb + kt + sc, lsB + c0 * 512);
        gload16(Bb + (size_t)(n0 + rA1) * ldb + kt + sc, lsB + c1 * 512);
        __syncthreads();

        s16x8 afrag[4], bfrag[4];
#pragma unroll
        for (int i = 0; i < 4; i++)
            afrag[i] = *(const s16x8*)(lsA + (wr + i * 16 + fr) * 32 + fq * 8);
#pragma unroll
        for (int j = 0; j < 4; j++)
            bfrag[j] = *(const s16x8*)(lsB + (wc + j * 16 + fr) * 32 + fq * 8);
#pragma unroll
        for (int i = 0; i < 4; i++)
#pragma unroll
            for (int j = 0; j < 4; j++)
                MFMA_BF16(acc[i][j], afrag[i], bfrag[j]);
        __syncthreads();
    }

    asm volatile("s_nop 7\ns_nop 7\ns_nop 7");

    {
        ushort* C = (ushort*)Cv + coff;
#pragma unroll
        for (int i = 0; i < 4; i++)
#pragma unroll
            for (int j = 0; j < 4; j++)
#pragma unroll
                for (int r = 0; r < 4; r++) {
                    const int row = m0 + wr + i * 16 + fq * 4 + r;
                    const int col = n0 + wc + j * 16 + fr;
                    float val = acc[i][j][r];
                    if (MODE == 1) val += 1.0f / (float)(Tt - row);  // feature alibi
                    C[(size_t)row * ldc + col] = f2bf(val);
                }
    }
}

// ---------------- scores: part[s][bh][f][g] = sum_{t in split s} q[t,f] k[t,g] ----------------

__global__ __launch_bounds__(256) void scores_kernel(const ushort* __restrict__ q,
        const ushort* __restrict__ k, float* __restrict__ part) {
    __shared__ float lsQ[32][128];
    __shared__ float lsK[32][128];
    const int tid = threadIdx.x;
    const int s = blockIdx.x, bh = blockIdx.y;
    const int b = bh >> 4, h = bh & 15;
    const size_t base = (size_t)b * ((size_t)Tt * Dd) + (size_t)h * 128;
    const ushort* qb = q + base;
    const ushort* kb = k + base;
    const int ty = tid >> 4, tx = tid & 15;
    const int f0 = ty * 8, g0 = tx * 8;

    float acc[8][8];
#pragma unroll
    for (int i = 0; i < 8; i++)
#pragma unroll
        for (int j = 0; j < 8; j++) acc[i][j] = 0.f;

    for (int ch = 0; ch < 8; ch++) {
        const int t0 = s * 256 + ch * 32;
#pragma unroll
        for (int ii = 0; ii < 4; ii++) {
            const int e = ii * 1024 + tid * 4;
            const int r = e >> 7, cc = e & 127;
            const size_t ga = (size_t)(t0 + r) * Dd + cc;
            const ushort4 v4 = *(const ushort4*)(qb + ga);
            f32x4 qf = {bf2f(v4.x), bf2f(v4.y), bf2f(v4.z), bf2f(v4.w)};
            *(f32x4*)&lsQ[r][cc] = qf;
            const ushort4 w4 = *(const ushort4*)(kb + ga);
            f32x4 kf = {bf2f(w4.x), bf2f(w4.y), bf2f(w4.z), bf2f(w4.w)};
            *(f32x4*)&lsK[r][cc] = kf;
        }
        __syncthreads();
#pragma unroll 4
        for (int tl = 0; tl < 32; tl++) {
            float qv[8], kv[8];
            *(f32x4*)&qv[0] = *(const f32x4*)&lsQ[tl][f0];
            *(f32x4*)&qv[4] = *(const f32x4*)&lsQ[tl][f0 + 4];
            *(f32x4*)&kv[0] = *(const f32x4*)&lsK[tl][g0];
            *(f32x4*)&kv[4] = *(const f32x4*)&lsK[tl][g0 + 4];
#pragma unroll
            for (int i = 0; i < 8; i++)
#pragma unroll
                for (int j = 0; j < 8; j++)
                    acc[i][j] = fmaf(qv[i], kv[j], acc[i][j]);
        }
        __syncthreads();
    }
    float* pb = part + ((size_t)s * 64 + bh) * 16384;
#pragma unroll
    for (int i = 0; i < 8; i++) {
        f32x4 o0 = {acc[i][0], acc[i][1], acc[i][2], acc[i][3]};
        f32x4 o1 = {acc[i][4], acc[i][5], acc[i][6], acc[i][7]};
        *(f32x4*)&pb[(f0 + i) * 128 + g0] = o0;
        *(f32x4*)&pb[(f0 + i) * 128 + g0 + 4] = o1;
    }
}

// ---------------- softmax over g: wts[bh][f][g] bf16 ----------------

__global__ __launch_bounds__(256) void softmax_kernel(const float* __restrict__ part,
                                                      ushort* __restrict__ wts) {
    const int tid = threadIdx.x;
    const int wv = tid >> 6, lane = tid & 63;
    const int row = blockIdx.x * 4 + wv;
    const float* p = part + (size_t)row * 128 + lane * 2;
    float v0 = 0.f, v1 = 0.f;
#pragma unroll
    for (int s = 0; s < 8; s++) {
        const float2 t = *(const float2*)(p + (size_t)s * 1048576);
        v0 += t.x; v1 += t.y;
    }
    const float sc = 0.088388347648318447f;  // 1/sqrt(128)
    v0 *= sc; v1 *= sc;
    float m = fmaxf(v0, v1);
#pragma unroll
    for (int off = 32; off > 0; off >>= 1) m = fmaxf(m, __shfl_xor(m, off));
    const float e0 = __expf(v0 - m), e1 = __expf(v1 - m);
    float smv = e0 + e1;
#pragma unroll
    for (int off = 32; off > 0; off >>= 1) smv += __shfl_xor(smv, off);
    const float inv = 1.0f / smv;
    ushort2 o; o.x = f2bf(e0 * inv); o.y = f2bf(e1 * inv);
    *(ushort2*)(wts + (size_t)row * 128 + lane * 2) = o;
}

// ---------------- launch ----------------

extern "C" void kernel_launch(void* const* d_in, const int* in_sizes, int n_in,
                              void* d_out, int out_size, void* d_ws, size_t ws_size,
                              hipStream_t stream) {
    const float* x  = (const float*)d_in[0];
    const float* Wq = (const float*)d_in[1];
    const float* Wk = (const float*)d_in[2];
    const float* Wv = (const float*)d_in[3];
    const float* Wp = (const float*)d_in[4];
    const float* bp = (const float*)d_in[5];
    float* out = (float*)d_out;
    char* ws = (char*)d_ws;

    ushort* xb   = (ushort*)(ws);
    ushort* Wt   = (ushort*)(ws + (33ull << 20));
    ushort* q    = (ushort*)(ws + (65ull << 20));
    ushort* k    = (ushort*)(ws + (97ull << 20));
    ushort* v    = (ushort*)(ws + (129ull << 20));
    float*  part = (float*) (ws + (161ull << 20));
    ushort* wts  = (ushort*)(ws + (193ull << 20));
    ushort* ctx  = xb;  // xb dead after v-GEMM; reuse for ctx

    const size_t WSZ = (size_t)Dd * Dd;

    // allow 128 KiB dynamic LDS for the 8-phase GEMM
    static_cast<void>(hipFuncSetAttribute((const void*)gemm256_kernel<0>,
        hipFuncAttributeMaxDynamicSharedMemorySize, 131072));
    static_cast<void>(hipFuncSetAttribute((const void*)gemm256_kernel<2>,
        hipFuncAttributeMaxDynamicSharedMemorySize, 131072));

    convx_kernel<<<2048, 256, 0, stream>>>(x, xb);
    transw_kernel<<<dim3(32, 32, 4), 256, 0, stream>>>(Wq, Wk, Wv, Wp, Wt);

    // q, k, v projections: [8192,2048] x [2048,2048], 256 blocks (1/CU)
    gemm256_kernel<0><<<256, 512, 131072, stream>>>(xb, Wt,           q, nullptr, 2048, 2048, 2048, 2048);
    gemm256_kernel<0><<<256, 512, 131072, stream>>>(xb, Wt + WSZ,     k, nullptr, 2048, 2048, 2048, 2048);
    gemm256_kernel<0><<<256, 512, 131072, stream>>>(xb, Wt + 2 * WSZ, v, nullptr, 2048, 2048, 2048, 2048);

    scores_kernel<<<dim3(8, 64), 256, 0, stream>>>(q, k, part);
    softmax_kernel<<<2048, 256, 0, stream>>>(part, wts);

    // ctx[t,f] = sum_g v[t,g] * wts[f,g] + alibi[t], per (b,h)
    gemm_kernel<1><<<dim3(1, 16, 64), 256, 0, stream>>>(v, wts, ctx, nullptr, 128, 2048, 128, 2048);

    // out = ctx @ Wp + bp  (fp32 out)
    gemm256_kernel<2><<<256, 512, 131072, stream>>>(ctx, Wt + 3 * WSZ, out, bp, 2048, 2048, 2048, 2048);
}

// Round 3
// 370.639 us; speedup vs baseline: 1.2310x; 1.0322x over previous
//
#include <hip/hip_runtime.h>
#include <hip/hip_bf16.h>

// FeatureAttention: B=4,T=2048,D=2048,H=16,HO=128
// alibi folded into ctx epilogue since softmax rows sum to 1.

#define Tt 2048
#define Dd 2048
#define Mm 8192   // B*T

typedef __attribute__((ext_vector_type(4))) float f32x4;
typedef __attribute__((ext_vector_type(8))) short s16x8;
static_assert(sizeof(s16x8) == 16, "frag size");

typedef const __attribute__((address_space(1))) void* gptr_t;
typedef __attribute__((address_space(3))) void* lptr_t;

__device__ __forceinline__ float bf2f(ushort u) {
    union { unsigned int i; float f; } c; c.i = ((unsigned int)u) << 16; return c.f;
}
__device__ __forceinline__ ushort f2bf(float f) {
    union { float f; unsigned int i; } c; c.f = f;
    return (ushort)((c.i + 0x7FFFu + ((c.i >> 16) & 1u)) >> 16);
}
__device__ __forceinline__ void gload16(const void* g, void* l) {
    __builtin_amdgcn_global_load_lds((gptr_t)g, (lptr_t)l, 16, 0, 0);
}
__device__ __forceinline__ s16x8 ldfrag(const char* p) { return *(const s16x8*)p; }

#define MFMA_BF16(d, a, b) \
    asm("v_mfma_f32_16x16x32_bf16 %0, %1, %2, %0" : "+v"(d) : "v"(a), "v"(b))

// ---------------- conversions ----------------

__global__ __launch_bounds__(256) void convx_kernel(const float* __restrict__ x,
                                                    ushort* __restrict__ xb) {
    const int idx = blockIdx.x * 256 + threadIdx.x;
    const int stride = gridDim.x * 256;
    for (int i = idx; i < Mm * Dd / 4; i += stride) {
        const float4 v = *(const float4*)(x + (size_t)i * 4);
        ushort4 o; o.x = f2bf(v.x); o.y = f2bf(v.y); o.z = f2bf(v.z); o.w = f2bf(v.w);
        *(ushort4*)(xb + (size_t)i * 4) = o;
    }
}

// W [K=d_in][N=d_out] fp32 -> Wt [N][K] bf16
__global__ __launch_bounds__(256) void transw_kernel(const float* __restrict__ W0,
        const float* __restrict__ W1, const float* __restrict__ W2,
        const float* __restrict__ W3, ushort* __restrict__ Wt) {
    __shared__ float tile[64][65];
    const int z = blockIdx.z;
    const float* W = (z == 0) ? W0 : (z == 1) ? W1 : (z == 2) ? W2 : W3;
    ushort* dst = Wt + (size_t)z * ((size_t)Dd * Dd);
    const int n0 = blockIdx.x * 64, k0 = blockIdx.y * 64;
    const int r4 = threadIdx.x >> 6, c = threadIdx.x & 63;
#pragma unroll
    for (int i = 0; i < 16; i++) {
        const int row = i * 4 + r4;
        tile[row][c] = W[(size_t)(k0 + row) * Dd + n0 + c];
    }
    __syncthreads();
#pragma unroll
    for (int i = 0; i < 16; i++) {
        const int row = i * 4 + r4;
        dst[(size_t)(n0 + row) * Dd + k0 + c] = f2bf(tile[c][row]);
    }
}

// ---------------- 256x256 8-phase GEMM: C[M,N] = A[M,K] * Bt[N,K]^T ----------------
// bf16 in, fp32 acc. MODE 0: C bf16 (z-batched over B/C via strides).
// MODE 2: C fp32 + bias.
// 512 threads = 8 waves (2M x 4N), BK=64, 128 KiB LDS double-buffer,
// T2 XOR-swizzle, 1-phase-lookahead ds_reads with counted lgkmcnt,
// counted vmcnt(4) once per K-tile, setprio around MFMA clusters.

__device__ __forceinline__ void stage_half(char* ldsRegion, const ushort* gRegion,
                                           int ld, int half, int tid) {
#pragma unroll
    for (int j = 0; j < 2; j++) {
        const int Pb = half * 16384 + j * 8192 + (tid >> 6) * 1024;  // wave-uniform
        const int P = Pb + (tid & 63) * 16;                          // lane slot
        const int row = P >> 7;
        const int colb = (P ^ ((row & 7) << 4)) & 127;               // logical col bytes
        gload16(gRegion + (size_t)row * ld + (colb >> 1), ldsRegion + Pb);
    }
}

template <int MODE>
__global__ __launch_bounds__(512, 2) void gemm256_kernel(
        const ushort* __restrict__ A, const ushort* __restrict__ Bt,
        void* __restrict__ Cv, const float* __restrict__ bias,
        int Kdim, int lda, int ldb, int ldc,
        size_t bstride, size_t cstride) {
    extern __shared__ char lds[];   // 2 x (A 32768 + B 32768) = 131072 B

    const int tid = threadIdx.x;
    const int lane = tid & 63;
    const int w = tid >> 6;
    const int wr = w >> 2, wc = w & 3;        // 2 x 4 waves
    const int fr = lane & 15, fq = lane >> 4;

    // XCD-aware bijective swizzle (nwg per z = 256 = 8 XCDs x 32)
    const int bid = blockIdx.x;
    const int wg = (bid & 7) * 32 + (bid >> 3);
    const int m0 = (wg >> 3) * 256;
    const int n0 = (wg & 7) * 256;

    const ushort* Ag = A + (size_t)m0 * lda;
    const ushort* Bg = Bt + (size_t)blockIdx.z * bstride + (size_t)n0 * ldb;
    const int NT = Kdim >> 6;

    // per-thread invariant LDS read offsets (swizzle: row&7 == fr&7)
    const int aoff = wr * 16384 + fr * 128;
    const int boff = wc * 8192 + fr * 128;
    const int xo = (fr & 7) << 4;
    const int cp0 = (fq * 16) ^ xo;           // k-sub 0
    const int cp1 = (64 + fq * 16) ^ xo;      // k-sub 1

    f32x4 acc[8][4];
#pragma unroll
    for (int i = 0; i < 8; i++)
#pragma unroll
        for (int j = 0; j < 4; j++) acc[i][j] = {0.f, 0.f, 0.f, 0.f};

    s16x8 afX[4][2], afY[4][2], bf01[2][2], bf23[2][2];

    // ---- prologue: tile 0 (4 halves) + A(1); then reads for P0(0) ----
    {
        char* b0 = lds;
        char* b1 = lds + 65536;
        stage_half(b0,         Ag, lda, 0, tid);
        stage_half(b0,         Ag, lda, 1, tid);
        stage_half(b0 + 32768, Bg, ldb, 0, tid);
        stage_half(b0 + 32768, Bg, ldb, 1, tid);
        if (NT > 1) {
            stage_half(b1, Ag + 64, lda, 0, tid);
            stage_half(b1, Ag + 64, lda, 1, tid);
        }
        __builtin_amdgcn_sched_barrier(0);
        if (NT > 1) asm volatile("s_waitcnt vmcnt(4)" ::: "memory");
        else        asm volatile("s_waitcnt vmcnt(0)" ::: "memory");
        __builtin_amdgcn_s_barrier();
        const char* Ab = b0 + aoff;
        const char* Bb = b0 + 32768 + boff;
#pragma unroll
        for (int m = 0; m < 4; m++) {
            afX[m][0] = ldfrag(Ab + m * 2048 + cp0);
            afX[m][1] = ldfrag(Ab + m * 2048 + cp1);
        }
#pragma unroll
        for (int n = 0; n < 2; n++) {
            bf01[n][0] = ldfrag(Bb + n * 2048 + cp0);
            bf01[n][1] = ldfrag(Bb + n * 2048 + cp1);
        }
        __builtin_amdgcn_sched_barrier(0);
    }

    for (int t = 0; t < NT; ++t) {
        char* bufc = lds + (t & 1) * 65536;
        char* bufn = lds + ((t & 1) ^ 1) * 65536;
        const char* Ab = bufc + aoff;
        const char* Bb = bufc + 32768 + boff;

        // ===== P0: issue bf23(t) [4]; stage B-lo(t+1); Q0 = afX x bf01 =====
#pragma unroll
        for (int n = 0; n < 2; n++) {
            bf23[n][0] = ldfrag(Bb + (n + 2) * 2048 + cp0);
            bf23[n][1] = ldfrag(Bb + (n + 2) * 2048 + cp1);
        }
        if (t + 1 < NT) stage_half(bufn + 32768, Bg + (size_t)(t + 1) * 64, ldb, 0, tid);
        __builtin_amdgcn_sched_barrier(0);
        __builtin_amdgcn_s_barrier();
        asm volatile("s_waitcnt lgkmcnt(4)" ::: "memory");   // drain afX+bf01
        __builtin_amdgcn_s_setprio(1);
#pragma unroll
        for (int k = 0; k < 2; k++)
#pragma unroll
            for (int m = 0; m < 4; m++)
#pragma unroll
                for (int n = 0; n < 2; n++) MFMA_BF16(acc[m][n], afX[m][k], bf01[n][k]);
        __builtin_amdgcn_s_setprio(0);
        __builtin_amdgcn_s_barrier();

        // ===== P1: issue afY(t) [8]; stage B-hi(t+1); Q1 = afX x bf23 =====
#pragma unroll
        for (int m = 0; m < 4; m++) {
            afY[m][0] = ldfrag(Ab + (m + 4) * 2048 + cp0);
            afY[m][1] = ldfrag(Ab + (m + 4) * 2048 + cp1);
        }
        if (t + 1 < NT) stage_half(bufn + 32768, Bg + (size_t)(t + 1) * 64, ldb, 1, tid);
        __builtin_amdgcn_sched_barrier(0);
        __builtin_amdgcn_s_barrier();
        asm volatile("s_waitcnt lgkmcnt(8)" ::: "memory");   // drain bf23
        __builtin_amdgcn_s_setprio(1);
#pragma unroll
        for (int k = 0; k < 2; k++)
#pragma unroll
            for (int m = 0; m < 4; m++)
#pragma unroll
                for (int n = 0; n < 2; n++) MFMA_BF16(acc[m][n + 2], afX[m][k], bf23[n][k]);
        __builtin_amdgcn_s_setprio(0);
        __builtin_amdgcn_s_barrier();

        // ===== P2: Q2 = afY x bf01 =====
        asm volatile("s_waitcnt lgkmcnt(0)" ::: "memory");   // drain afY
        __builtin_amdgcn_s_setprio(1);
#pragma unroll
        for (int k = 0; k < 2; k++)
#pragma unroll
            for (int m = 0; m < 4; m++)
#pragma unroll
                for (int n = 0; n < 2; n++) MFMA_BF16(acc[m + 4][n], afY[m][k], bf01[n][k]);
        __builtin_amdgcn_s_setprio(0);
        __builtin_amdgcn_s_barrier();

        // ===== P3: stage A(t+2); vmcnt; barrier; issue reads(t+1) [12]; Q3 =====
        if (t + 2 < NT) {
            stage_half(bufc, Ag + (size_t)(t + 2) * 64, lda, 0, tid);
            stage_half(bufc, Ag + (size_t)(t + 2) * 64, lda, 1, tid);
        }
        __builtin_amdgcn_sched_barrier(0);
        if (t + 2 < NT) asm volatile("s_waitcnt vmcnt(4)" ::: "memory");
        else            asm volatile("s_waitcnt vmcnt(0)" ::: "memory");
        __builtin_amdgcn_s_barrier();
        if (t + 1 < NT) {
            const char* nAb = bufn + aoff;
            const char* nBb = bufn + 32768 + boff;
#pragma unroll
            for (int m = 0; m < 4; m++) {
                afX[m][0] = ldfrag(nAb + m * 2048 + cp0);
                afX[m][1] = ldfrag(nAb + m * 2048 + cp1);
            }
#pragma unroll
            for (int n = 0; n < 2; n++) {
                bf01[n][0] = ldfrag(nBb + n * 2048 + cp0);
                bf01[n][1] = ldfrag(nBb + n * 2048 + cp1);
            }
        }
        __builtin_amdgcn_sched_barrier(0);
        __builtin_amdgcn_s_setprio(1);
#pragma unroll
        for (int k = 0; k < 2; k++)
#pragma unroll
            for (int m = 0; m < 4; m++)
#pragma unroll
                for (int n = 0; n < 2; n++) MFMA_BF16(acc[m + 4][n + 2], afY[m][k], bf23[n][k]);
        __builtin_amdgcn_s_setprio(0);
        __builtin_amdgcn_s_barrier();
    }

    asm volatile("s_nop 7\ns_nop 7\ns_nop 7");  // MFMA->VALU hazard guard

    if (MODE == 2) {
        float* C = (float*)Cv;
#pragma unroll
        for (int mi = 0; mi < 8; mi++)
#pragma unroll
            for (int ni = 0; ni < 4; ni++)
#pragma unroll
                for (int r = 0; r < 4; r++) {
                    const int row = m0 + wr * 128 + mi * 16 + fq * 4 + r;
                    const int col = n0 + wc * 64 + ni * 16 + fr;
                    C[(size_t)row * ldc + col] = acc[mi][ni][r] + bias[col];
                }
    } else {
        ushort* C = (ushort*)Cv + (size_t)blockIdx.z * cstride;
#pragma unroll
        for (int mi = 0; mi < 8; mi++)
#pragma unroll
            for (int ni = 0; ni < 4; ni++)
#pragma unroll
                for (int r = 0; r < 4; r++) {
                    const int row = m0 + wr * 128 + mi * 16 + fq * 4 + r;
                    const int col = n0 + wc * 64 + ni * 16 + fr;
                    C[(size_t)row * ldc + col] = f2bf(acc[mi][ni][r]);
                }
    }
}

// ---------------- 128x128 GEMM (small batched ctx GEMM) ----------------
// MODE 1: batched per (b,h) ctx GEMM, + alibi, C bf16.

template <int MODE>
__global__ __launch_bounds__(256, 2) void gemm_kernel(
        const ushort* __restrict__ A, const ushort* __restrict__ Bt,
        void* __restrict__ Cv, const float* __restrict__ bias,
        int Kdim, int lda, int ldb, int ldc) {
    __shared__ ushort lsA[128 * 32];
    __shared__ ushort lsB[128 * 32];

    const int tid = threadIdx.x;
    const int w = tid >> 6, lane = tid & 63;
    const int m0 = blockIdx.y * 128;
    const int n0 = blockIdx.x * 128;

    const ushort* Ab = A;
    const ushort* Bb = Bt;
    size_t coff = 0;
    if (MODE == 1) {
        const int z = blockIdx.z, b = z >> 4, h = z & 15;
        const size_t ao = (size_t)b * ((size_t)Tt * Dd) + (size_t)h * 128;
        Ab += ao; Bb += (size_t)z * (128 * 128); coff = ao;
    }

    const int sr = lane >> 2;
    const int sc = (lane & 3) * 8;
    const int c0 = w, c1 = w + 4;
    const int rA0 = c0 * 16 + sr, rA1 = c1 * 16 + sr;

    const int fr = lane & 15, fq = lane >> 4;
    const int wr = (w >> 1) * 64, wc = (w & 1) * 64;

    f32x4 acc[4][4];
#pragma unroll
    for (int i = 0; i < 4; i++)
#pragma unroll
        for (int j = 0; j < 4; j++) acc[i][j] = {0.f, 0.f, 0.f, 0.f};

    for (int kt = 0; kt < Kdim; kt += 32) {
        gload16(Ab + (size_t)(m0 + rA0) * lda + kt + sc, lsA + c0 * 512);
        gload16(Ab + (size_t)(m0 + rA1) * lda + kt + sc, lsA + c1 * 512);
        gload16(Bb + (size_t)(n0 + rA0) * ldb + kt + sc, lsB + c0 * 512);
        gload16(Bb + (size_t)(n0 + rA1) * ldb + kt + sc, lsB + c1 * 512);
        __syncthreads();

        s16x8 afrag[4], bfrag[4];
#pragma unroll
        for (int i = 0; i < 4; i++)
            afrag[i] = *(const s16x8*)(lsA + (wr + i * 16 + fr) * 32 + fq * 8);
#pragma unroll
        for (int j = 0; j < 4; j++)
            bfrag[j] = *(const s16x8*)(lsB + (wc + j * 16 + fr) * 32 + fq * 8);
#pragma unroll
        for (int i = 0; i < 4; i++)
#pragma unroll
            for (int j = 0; j < 4; j++)
                MFMA_BF16(acc[i][j], afrag[i], bfrag[j]);
        __syncthreads();
    }

    asm volatile("s_nop 7\ns_nop 7\ns_nop 7");

    {
        ushort* C = (ushort*)Cv + coff;
#pragma unroll
        for (int i = 0; i < 4; i++)
#pragma unroll
            for (int j = 0; j < 4; j++)
#pragma unroll
                for (int r = 0; r < 4; r++) {
                    const int row = m0 + wr + i * 16 + fq * 4 + r;
                    const int col = n0 + wc + j * 16 + fr;
                    float val = acc[i][j][r];
                    if (MODE == 1) val += 1.0f / (float)(Tt - row);  // feature alibi
                    C[(size_t)row * ldc + col] = f2bf(val);
                }
    }
}

// ---------------- scores: part[s][bh][f][g] = sum_{t in split s} q[t,f] k[t,g] ----------------

__global__ __launch_bounds__(256) void scores_kernel(const ushort* __restrict__ q,
        const ushort* __restrict__ k, float* __restrict__ part) {
    __shared__ float lsQ[32][128];
    __shared__ float lsK[32][128];
    const int tid = threadIdx.x;
    const int s = blockIdx.x, bh = blockIdx.y;
    const int b = bh >> 4, h = bh & 15;
    const size_t base = (size_t)b * ((size_t)Tt * Dd) + (size_t)h * 128;
    const ushort* qb = q + base;
    const ushort* kb = k + base;
    const int ty = tid >> 4, tx = tid & 15;
    const int f0 = ty * 8, g0 = tx * 8;

    float acc[8][8];
#pragma unroll
    for (int i = 0; i < 8; i++)
#pragma unroll
        for (int j = 0; j < 8; j++) acc[i][j] = 0.f;

    for (int ch = 0; ch < 8; ch++) {
        const int t0 = s * 256 + ch * 32;
#pragma unroll
        for (int ii = 0; ii < 4; ii++) {
            const int e = ii * 1024 + tid * 4;
            const int r = e >> 7, cc = e & 127;
            const size_t ga = (size_t)(t0 + r) * Dd + cc;
            const ushort4 v4 = *(const ushort4*)(qb + ga);
            f32x4 qf = {bf2f(v4.x), bf2f(v4.y), bf2f(v4.z), bf2f(v4.w)};
            *(f32x4*)&lsQ[r][cc] = qf;
            const ushort4 w4 = *(const ushort4*)(kb + ga);
            f32x4 kf = {bf2f(w4.x), bf2f(w4.y), bf2f(w4.z), bf2f(w4.w)};
            *(f32x4*)&lsK[r][cc] = kf;
        }
        __syncthreads();
#pragma unroll 4
        for (int tl = 0; tl < 32; tl++) {
            float qv[8], kv[8];
            *(f32x4*)&qv[0] = *(const f32x4*)&lsQ[tl][f0];
            *(f32x4*)&qv[4] = *(const f32x4*)&lsQ[tl][f0 + 4];
            *(f32x4*)&kv[0] = *(const f32x4*)&lsK[tl][g0];
            *(f32x4*)&kv[4] = *(const f32x4*)&lsK[tl][g0 + 4];
#pragma unroll
            for (int i = 0; i < 8; i++)
#pragma unroll
                for (int j = 0; j < 8; j++)
                    acc[i][j] = fmaf(qv[i], kv[j], acc[i][j]);
        }
        __syncthreads();
    }
    float* pb = part + ((size_t)s * 64 + bh) * 16384;
#pragma unroll
    for (int i = 0; i < 8; i++) {
        f32x4 o0 = {acc[i][0], acc[i][1], acc[i][2], acc[i][3]};
        f32x4 o1 = {acc[i][4], acc[i][5], acc[i][6], acc[i][7]};
        *(f32x4*)&pb[(f0 + i) * 128 + g0] = o0;
        *(f32x4*)&pb[(f0 + i) * 128 + g0 + 4] = o1;
    }
}

// ---------------- softmax over g: wts[bh][f][g] bf16 ----------------

__global__ __launch_bounds__(256) void softmax_kernel(const float* __restrict__ part,
                                                      ushort* __restrict__ wts) {
    const int tid = threadIdx.x;
    const int wv = tid >> 6, lane = tid & 63;
    const int row = blockIdx.x * 4 + wv;
    const float* p = part + (size_t)row * 128 + lane * 2;
    float v0 = 0.f, v1 = 0.f;
#pragma unroll
    for (int s = 0; s < 8; s++) {
        const float2 t = *(const float2*)(p + (size_t)s * 1048576);
        v0 += t.x; v1 += t.y;
    }
    const float sc = 0.088388347648318447f;  // 1/sqrt(128)
    v0 *= sc; v1 *= sc;
    float m = fmaxf(v0, v1);
#pragma unroll
    for (int off = 32; off > 0; off >>= 1) m = fmaxf(m, __shfl_xor(m, off));
    const float e0 = __expf(v0 - m), e1 = __expf(v1 - m);
    float smv = e0 + e1;
#pragma unroll
    for (int off = 32; off > 0; off >>= 1) smv += __shfl_xor(smv, off);
    const float inv = 1.0f / smv;
    ushort2 o; o.x = f2bf(e0 * inv); o.y = f2bf(e1 * inv);
    *(ushort2*)(wts + (size_t)row * 128 + lane * 2) = o;
}

// ---------------- launch ----------------

extern "C" void kernel_launch(void* const* d_in, const int* in_sizes, int n_in,
                              void* d_out, int out_size, void* d_ws, size_t ws_size,
                              hipStream_t stream) {
    const float* x  = (const float*)d_in[0];
    const float* Wq = (const float*)d_in[1];
    const float* Wk = (const float*)d_in[2];
    const float* Wv = (const float*)d_in[3];
    const float* Wp = (const float*)d_in[4];
    const float* bp = (const float*)d_in[5];
    float* out = (float*)d_out;
    char* ws = (char*)d_ws;

    ushort* xb   = (ushort*)(ws);
    ushort* Wt   = (ushort*)(ws + (33ull << 20));
    ushort* q    = (ushort*)(ws + (65ull << 20));
    ushort* k    = (ushort*)(ws + (97ull << 20));
    ushort* v    = (ushort*)(ws + (129ull << 20));
    float*  part = (float*) (ws + (161ull << 20));
    ushort* wts  = (ushort*)(ws + (193ull << 20));
    ushort* ctx  = xb;  // xb dead after qkv-GEMM; reuse for ctx

    const size_t WSZ = (size_t)Dd * Dd;          // elements per transposed weight
    const size_t QSTRIDE = (32ull << 20) / 2;    // q->k->v spacing in elements

    static_cast<void>(hipFuncSetAttribute((const void*)gemm256_kernel<0>,
        hipFuncAttributeMaxDynamicSharedMemorySize, 131072));
    static_cast<void>(hipFuncSetAttribute((const void*)gemm256_kernel<2>,
        hipFuncAttributeMaxDynamicSharedMemorySize, 131072));

    convx_kernel<<<2048, 256, 0, stream>>>(x, xb);
    transw_kernel<<<dim3(32, 32, 4), 256, 0, stream>>>(Wq, Wk, Wv, Wp, Wt);

    // q, k, v projections fused into one z=3 dispatch
    gemm256_kernel<0><<<dim3(256, 1, 3), 512, 131072, stream>>>(
        xb, Wt, q, nullptr, 2048, 2048, 2048, 2048, WSZ, QSTRIDE);

    scores_kernel<<<dim3(8, 64), 256, 0, stream>>>(q, k, part);
    softmax_kernel<<<2048, 256, 0, stream>>>(part, wts);

    // ctx[t,f] = sum_g v[t,g] * wts[f,g] + alibi[t], per (b,h)
    gemm_kernel<1><<<dim3(1, 16, 64), 256, 0, stream>>>(v, wts, ctx, nullptr, 128, 2048, 128, 2048);

    // out = ctx @ Wp + bp  (fp32 out)
    gemm256_kernel<2><<<dim3(256, 1, 1), 512, 131072, stream>>>(
        ctx, Wt + 3 * WSZ, out, bp, 2048, 2048, 2048, 2048, 0, 0);
}